// Round 15
// baseline (445.511 us; speedup 1.0000x reference)
//
#include <hip/hip_runtime.h>

#define MAPN 250000      // 500*500
#define NPIX 2097152     // 1024*2048

typedef unsigned short ushort_t;
typedef __attribute__((ext_vector_type(4))) float f32x4;

__device__ inline ushort_t f2bf(float f){
  unsigned u = __float_as_uint(f);
  u = (u + 0x7fffu + ((u >> 16) & 1u)) >> 16;
  return (ushort_t)u;
}
__device__ inline float bf2f(ushort_t h){ return __uint_as_float(((unsigned)h) << 16); }

// e4m3fn -> f32 (branchless-ish; denormals handled)
__device__ inline float f82f(unsigned b){
  unsigned e = (b>>3)&15u, m = b&7u;
  float v = e ? __uint_as_float(((e+120u)<<23)|(m<<20)) : (float)m * 0.001953125f;
  return (b & 0x80u) ? -v : v;
}

__device__ __forceinline__ void glds16(const void* g, void* l){
  __builtin_amdgcn_global_load_lds((const __attribute__((address_space(1))) unsigned int*)g,
                                   (__attribute__((address_space(3))) unsigned int*)l, 16, 0, 0);
}

// ---------------- input-format helpers ----------------
__device__ inline int read_mask(const void* p, int i, int t){
  if (t==0) return ((const int*)p)[i] != 0;
  if (t==1) return ((const unsigned char*)p)[i] != 0;
  if (t==3) return ((const long long*)p)[i] != 0;
  return ((const float*)p)[i] != 0.0f;
}
__device__ inline int read_idx(const void* p, int i, int t){
  if (t==1) return (int)((const long long*)p)[i];
  return ((const int*)p)[i];
}

__global__ void detect_kernel(const int* __restrict__ mask_w, const int* __restrict__ idx_w,
                              int* __restrict__ flags, int* __restrict__ maxidx){
  int tid = threadIdx.x;
  int orv=0, modd=0, inz=0;
  for (int i=tid;i<4096;i+=256) orv |= mask_w[i];
  for (int i=tid;i<2048;i+=256) modd += (mask_w[2*i+1]!=0);
  for (int i=tid;i<2048;i+=256) inz  += (idx_w[2*i+1]!=0);
  __shared__ int sOr[256], sM[256], sI[256];
  sOr[tid]=orv; sM[tid]=modd; sI[tid]=inz; __syncthreads();
  for (int o=128;o;o>>=1){ if(tid<o){ sOr[tid]|=sOr[tid+o]; sM[tid]+=sM[tid+o]; sI[tid]+=sI[tid+o]; } __syncthreads(); }
  if (tid==0){
    int o = sOr[0];
    int mt;
    if ((o & ~1) == 0)               mt = (sM[0] > 0) ? 0 : 3;
    else if ((o & ~0x01010101) == 0) mt = 1;
    else                             mt = 2;
    flags[0] = mt;
    flags[1] = (sI[0] > 0) ? 0 : 1;
    maxidx[0] = 0;
  }
}

// ---------------- feature transpose CHW -> HWC (fp32 -> fp8) ----------------
__global__ void feat_transpose(const float* __restrict__ f, unsigned char* __restrict__ out){
  __shared__ float tile[64][65];
  int tid = threadIdx.x;
  int y = blockIdx.y;
  int x0 = blockIdx.x * 64;
  #pragma unroll
  for (int pass=0; pass<16; pass++){
    int c = pass*4 + (tid>>6);
    int x = x0 + (tid & 63);
    tile[c][tid & 63] = f[(size_t)c*131072 + (size_t)y*512 + x];
  }
  __syncthreads();
  #pragma unroll
  for (int pass=0; pass<16; pass++){
    int xl = pass*4 + (tid>>6);
    int c  = tid & 63;
    int q = __builtin_amdgcn_cvt_pk_fp8_f32(tile[c][xl], 0.0f, 0, false);
    out[((size_t)y*512 + x0 + xl)*64 + c] = (unsigned char)(q & 0xff);
  }
}

// ---------------- mask compaction scan ----------------
__global__ void scan_count(const void* __restrict__ mask, const int* __restrict__ flags,
                           int* __restrict__ blkSums){
  int t = flags[0];
  int tid = threadIdx.x;
  int base = blockIdx.x*1024 + tid*4;
  int s = 0;
  #pragma unroll
  for (int j=0;j<4;j++) s += read_mask(mask, base+j, t);
  __shared__ int red[256];
  red[tid] = s; __syncthreads();
  for (int o=128;o;o>>=1){ if (tid<o) red[tid]+=red[tid+o]; __syncthreads(); }
  if (tid==0) blkSums[blockIdx.x] = red[0];
}

__global__ void scan_offsets(const int* __restrict__ blkSums, int* __restrict__ blkOffs){
  __shared__ int tsum[256];
  int tid = threadIdx.x;
  int loc[8]; int s=0;
  #pragma unroll
  for (int j=0;j<8;j++){ loc[j]=blkSums[tid*8+j]; s+=loc[j]; }
  tsum[tid]=s; __syncthreads();
  for (int o=1;o<256;o<<=1){
    int v = (tid>=o)? tsum[tid-o] : 0;
    __syncthreads();
    tsum[tid] += v;
    __syncthreads();
  }
  int run = tsum[tid]-s;
  #pragma unroll
  for (int j=0;j<8;j++){ blkOffs[tid*8+j]=run; run+=loc[j]; }
  if (tid==255) blkOffs[2048]=run;
}

__global__ void build_table(const void* __restrict__ mask, const int* __restrict__ flags,
                            const int* __restrict__ blkOffs, int* __restrict__ table){
  int t = flags[0];
  int tid = threadIdx.x;
  int base = blockIdx.x*1024 + tid*4;
  int mv[4]; int s=0;
  #pragma unroll
  for (int j=0;j<4;j++){ mv[j]=read_mask(mask, base+j, t); s+=mv[j]; }
  __shared__ int red[256];
  red[tid]=s; __syncthreads();
  for (int o=1;o<256;o<<=1){
    int v = (tid>=o)? red[tid-o] : 0;
    __syncthreads();
    red[tid]+=v;
    __syncthreads();
  }
  int excl = red[tid]-s + blkOffs[blockIdx.x];
  int total = blkOffs[2048];
  #pragma unroll
  for (int j=0;j<4;j++){
    int p = base+j;
    int pos;
    if (mv[j]){ pos = excl; excl++; }
    else      { pos = total + (p - excl); }
    table[pos] = p;
  }
}

// ---------------- max(idx) ----------------
__global__ void max_idx_kernel(const void* __restrict__ idxp, const int* __restrict__ flags,
                               int* __restrict__ mx){
  int t = flags[1];
  int m = 0;
  for (int i = blockIdx.x*blockDim.x + threadIdx.x; i < MAPN; i += gridDim.x*blockDim.x)
    m = max(m, read_idx(idxp, i, t));
  #pragma unroll
  for (int o=32;o;o>>=1) m = max(m, __shfl_down(m, o));
  if ((threadIdx.x & 63) == 0) atomicMax(mx, m);
}

// ---------------- gather + on-the-fly bilinear (fp8 in) -> fp8 memory ----------------
__global__ void gather_kernel(const void* __restrict__ idxp, const int* __restrict__ flags,
                              const int* __restrict__ mxp, const int* __restrict__ table,
                              const unsigned char* __restrict__ Fhwc, const float* __restrict__ rgb,
                              unsigned char* __restrict__ mem_f8, float* __restrict__ out_obs,
                              float* __restrict__ out_rgb){
  int cell = blockIdx.x*4 + (threadIdx.x>>6);
  int lane = threadIdx.x & 63;
  int t = flags[1];
  int mx = *mxp;
  int idx = read_idx(idxp, cell, t);
  bool m = idx < mx;
  float v = 0.0f, r = 0.0f;
  if (m){
    int p = table[idx];
    int py = p >> 11, px = p & 2047;
    float fy = py * (255.0f/1023.0f);
    int y0 = (int)fy; float wy = fy - (float)y0; int y1 = min(y0+1, 255);
    float fx = px * (511.0f/2047.0f);
    int x0 = (int)fx; float wx = fx - (float)x0; int x1 = min(x0+1, 511);
    const unsigned char* f00 = Fhwc + ((size_t)y0*512 + x0)*64;
    const unsigned char* f01 = Fhwc + ((size_t)y0*512 + x1)*64;
    const unsigned char* f10 = Fhwc + ((size_t)y1*512 + x0)*64;
    const unsigned char* f11 = Fhwc + ((size_t)y1*512 + x1)*64;
    float w00=(1.0f-wy)*(1.0f-wx), w01=(1.0f-wy)*wx, w10=wy*(1.0f-wx), w11=wy*wx;
    v = w00*f82f(f00[lane]) + w01*f82f(f01[lane]) + w10*f82f(f10[lane]) + w11*f82f(f11[lane]);
    if (lane < 3) r = rgb[(size_t)p*3 + lane];
  }
  int q = __builtin_amdgcn_cvt_pk_fp8_f32(v, 0.0f, 0, false);
  mem_f8[(size_t)cell*64 + lane] = (unsigned char)(q & 0xff);
  if (lane == 0) out_obs[cell] = m ? 1.0f : 0.0f;
  if (lane < 3)  out_rgb[(size_t)cell*3 + lane] = r;
}

// ---------------- weight prep: OIHW fp32 -> fragment-major fp8, per-CO pow2 scale ----------------
__device__ void wprep_body(const float* __restrict__ w, unsigned char* __restrict__ out,
                           int O, int I, int CIPAD, int KK, int co){
  int n = KK*CIPAD;
  int NFS = (O+15)>>4;
  int KC  = CIPAD>>5;
  float mx = 0.f;
  for (int e=threadIdx.x; e<n; e+=256){
    int ci = e % CIPAD;
    if (ci < I){
      int t = e / CIPAD;
      mx = fmaxf(mx, fabsf(w[((size_t)co*I + ci)*KK + t]));
    }
  }
  __shared__ float red[256];
  red[threadIdx.x]=mx; __syncthreads();
  for (int o=128;o;o>>=1){ if(threadIdx.x<o) red[threadIdx.x]=fmaxf(red[threadIdx.x],red[threadIdx.x+o]); __syncthreads(); }
  float m = red[0];
  float sc = (m > 0.f) ? exp2f(floorf(log2f(224.0f/m))) : 1.0f;
  for (int e=threadIdx.x; e<n; e+=256){
    int t = e / CIPAD, ci = e % CIPAD;
    float v = (ci < I) ? w[((size_t)co*I + ci)*KK + t]*sc : 0.0f;
    int q = __builtin_amdgcn_cvt_pk_fp8_f32(v, 0.0f, 0, false);
    int kc = ci>>5, g=(ci>>3)&3, j=ci&7;
    int l = g*16 + (co&15);
    size_t pos = ((size_t)(t*KC + kc)*NFS + (co>>4))*512 + l*8 + j;
    out[pos] = (unsigned char)(q & 0xff);
  }
}

// merged: blocks 0-127 -> L1, 128-191 -> L2, 192-239 -> L3, 240-287 -> L4
__global__ void wprep_all(const float* __restrict__ w1, unsigned char* __restrict__ o1,
                          const float* __restrict__ w2, unsigned char* __restrict__ o2,
                          const float* __restrict__ w3, unsigned char* __restrict__ o3,
                          const float* __restrict__ w4, unsigned char* __restrict__ o4){
  int b = blockIdx.x;
  if      (b < 128) wprep_body(w1, o1, 128, 64, 64, 49, b);
  else if (b < 192) wprep_body(w2, o2, 64, 128, 128, 9, b-128);
  else if (b < 240) wprep_body(w3, o3, 48, 64, 64, 9, b-192);
  else              wprep_body(w4, o4, 48, 48, 64, 9, b-240);
}

// ---------------- unified 2D-tile fp8 MFMA conv, per-kh B batch (2 barriers/kh) ----------------
template<int CI, int CO, int COPAD, int KS, int PAD, bool HASBN, int CIREAL,
         int TR, int WM, int WN>
__global__ __launch_bounds__(256, 2) void conv2d_f8(const void* __restrict__ in,
                                                    const unsigned char* __restrict__ wt,
                                                    const float* __restrict__ scsh,
                                                    ushort_t* __restrict__ out,
                                                    float* __restrict__ partials){
  constexpr int TCOL = 64;
  constexpr int ECOL = TCOL + 2*PAD;
  constexpr int E    = TR*ECOL;
  constexpr int MF   = TR*4;
  constexpr int MI   = MF/WM;
  constexpr int NFS  = CO/16;
  constexpr int NFW  = NFS/WN;
  constexpr int KC   = CI/32;
  constexpr int CIG  = CI/8;
  constexpr int TB   = CO*CI;
  constexpr int NSL  = TB/1024;
  constexpr int TOT  = E*CIG;
  constexpr int PASSES = (TOT+255)/256;
  constexpr int SCN = HASBN ? CIREAL : 1;

  __shared__ unsigned char sA[E*CI + 128];
  __shared__ unsigned char sB[KS*TB];
  __shared__ float sStat[4][NFW][16][2];
  __shared__ float sSc[SCN], sSh[SCN];

  const int tid = threadIdx.x, lane = tid & 63, wv = tid >> 6;
  const int wm = wv / WN, wn = wv % WN;
  const int cc = blockIdx.x & 7;
  const int rb = blockIdx.x >> 3;
  const int x0 = cc*TCOL, yb = rb*TR;

  const ushort_t* inb = (const ushort_t*)in;
  const unsigned char* in8 = (const unsigned char*)in;

  if (HASBN){
    for (int i=tid;i<CIREAL;i+=256){ sSc[i]=scsh[i]; sSh[i]=scsh[CIREAL+i]; }
    __syncthreads();
  }

  int ebase[MI], frow[MI], fcolb[MI];
  #pragma unroll
  for (int mi=0;mi<MI;mi++){
    int f = wm*MI + mi;
    frow[mi]  = f >> 2;
    fcolb[mi] = (f & 3) * 16;
    ebase[mi] = frow[mi]*ECOL + fcolb[mi] + (lane & 15);
  }

  f32x4 acc[MI][NFW];
  #pragma unroll
  for (int mi=0;mi<MI;mi++)
    #pragma unroll
    for (int ni=0;ni<NFW;ni++) acc[mi][ni] = (f32x4)0.0f;

  for (int kh=0; kh<KS; kh++){
    #pragma unroll
    for (int i=0;i<PASSES;i++){
      int c = i*256 + tid;
      if ((TOT % 256 == 0) || c < TOT){
        int e = c / CIG, ci8 = (c % CIG)*8;
        int row = e / ECOL, col = e % ECOL;
        int yy = yb + row + kh - PAD;
        int xx = x0 + col - PAD;
        uint2 q = make_uint2(0u,0u);
        bool ok = ((unsigned)yy < 500u) && ((unsigned)xx < 500u) && (!HASBN || ci8 < CIREAL);
        if (ok){
          if (HASBN){
            uint4 v = *(const uint4*)(inb + ((size_t)yy*500 + xx)*CI + ci8);
            ushort_t* hv = (ushort_t*)&v;
            float f[8];
            #pragma unroll
            for (int j=0;j<8;j++)
              f[j] = fmaxf(fmaf(bf2f(hv[j]), sSc[ci8+j], sSh[ci8+j]), 0.0f);
            int d0 = __builtin_amdgcn_cvt_pk_fp8_f32(f[0], f[1], 0, false);
            d0     = __builtin_amdgcn_cvt_pk_fp8_f32(f[2], f[3], d0, true);
            int d1 = __builtin_amdgcn_cvt_pk_fp8_f32(f[4], f[5], 0, false);
            d1     = __builtin_amdgcn_cvt_pk_fp8_f32(f[6], f[7], d1, true);
            q = make_uint2((unsigned)d0, (unsigned)d1);
          } else {
            q = *(const uint2*)(in8 + ((size_t)yy*500 + xx)*CI + ci8);
          }
        }
        unsigned wa = ((unsigned)(e*CI + ci8)) ^ ((unsigned)(e&15)<<3);
        *(uint2*)(sA + wa) = q;
      }
    }
    {
      const char* wsrc = (const char*)wt + (size_t)kh*KS*TB;
      for (int s=wv; s<KS*NSL; s+=4)
        glds16(wsrc + (size_t)s*1024 + lane*16, &sB[s*1024]);
    }
    __syncthreads();

    for (int kw=0; kw<KS; kw++){
      const unsigned char* bb = sB + kw*TB;
      #pragma unroll
      for (int kc=0;kc<KC;kc++){
        long long bfr[NFW];
        #pragma unroll
        for (int ni=0;ni<NFW;ni++)
          bfr[ni] = *(const long long*)(bb + (((kc*NFS + wn*NFW + ni)<<9) + lane*8));
        #pragma unroll
        for (int mi=0;mi<MI;mi++){
          int e = ebase[mi] + kw;
          unsigned ra = ((unsigned)(e*CI + kc*32 + (lane>>4)*8)) ^ ((unsigned)(e&15)<<3);
          long long af = *(const long long*)(sA + ra);
          #pragma unroll
          for (int ni=0;ni<NFW;ni++)
            acc[mi][ni] = __builtin_amdgcn_mfma_f32_16x16x32_fp8_fp8(af, bfr[ni], acc[mi][ni], 0,0,0);
        }
      }
    }
    __syncthreads();
  }

  #pragma unroll
  for (int ni=0;ni<NFW;ni++){
    float ps=0.f, pq=0.f;
    #pragma unroll
    for (int mi=0;mi<MI;mi++){
      int colb = fcolb[mi] + (lane>>4)*4;
      size_t rowoff = (size_t)(yb + frow[mi])*500;
      #pragma unroll
      for (int j=0;j<4;j++){
        float v = acc[mi][ni][j];
        int colAbs = x0 + colb + j;
        if (colAbs < 500){
          ps += v; pq += v*v;
          out[(rowoff + colAbs)*COPAD + wn*(NFW*16) + ni*16 + (lane&15)] = f2bf(v);
        }
      }
    }
    ps += __shfl_xor(ps, 16); pq += __shfl_xor(pq, 16);
    ps += __shfl_xor(ps, 32); pq += __shfl_xor(pq, 32);
    if (lane < 16){ sStat[wv][ni][lane][0]=ps; sStat[wv][ni][lane][1]=pq; }
  }
  __syncthreads();
  if (tid < CO){
    int wn_ = tid / (NFW*16);
    int r = tid % (NFW*16);
    int ni_ = r >> 4, col = r & 15;
    float s = 0.f, q = 0.f;
    #pragma unroll
    for (int m=0;m<WM;m++){
      s += sStat[m*WN + wn_][ni_][col][0];
      q += sStat[m*WN + wn_][ni_][col][1];
    }
    partials[(size_t)blockIdx.x*(2*CO) + tid]      = s;
    partials[(size_t)blockIdx.x*(2*CO) + CO + tid] = q;
  }
}

// ---------------- BN: reduce per-block partials -> scale/shift ----------------
__global__ void bn_reduce2(const float* __restrict__ partials, int nblk, int CO,
                           const float* __restrict__ g, const float* __restrict__ b,
                           float* __restrict__ scsh){
  int c = blockIdx.x;
  float s=0.f, q=0.f;
  for (int i=threadIdx.x; i<nblk; i+=256){
    s += partials[(size_t)i*(2*CO) + c];
    q += partials[(size_t)i*(2*CO) + CO + c];
  }
  __shared__ float rs[256], rq[256];
  rs[threadIdx.x]=s; rq[threadIdx.x]=q; __syncthreads();
  for (int o=128;o;o>>=1){
    if (threadIdx.x<o){ rs[threadIdx.x]+=rs[threadIdx.x+o]; rq[threadIdx.x]+=rq[threadIdx.x+o]; }
    __syncthreads();
  }
  if (threadIdx.x==0){
    float mean = rs[0]*(1.0f/(float)MAPN);
    float var  = rq[0]*(1.0f/(float)MAPN) - mean*mean;
    float inv  = rsqrtf(var + 1e-5f);
    float sc   = g[c]*inv;
    scsh[c]    = sc;
    scsh[CO+c] = b[c] - mean*sc;
  }
}

// ---------------- final 1x1 conv + bias (fused input BN+ReLU), fp32, NCHW out ----------------
__global__ void conv5_kernel(const ushort_t* __restrict__ in, const float* __restrict__ w,
                             const float* __restrict__ bias, const float* __restrict__ scsh,
                             float* __restrict__ out){
  __shared__ float sw[21*48];
  __shared__ float sb[21];
  __shared__ float sc[48], sh[48];
  for (int i=threadIdx.x;i<1008;i+=256) sw[i]=w[i];
  if (threadIdx.x<21) sb[threadIdx.x]=bias[threadIdx.x];
  if (threadIdx.x<48){ sc[threadIdx.x]=scsh[threadIdx.x]; sh[threadIdx.x]=scsh[48+threadIdx.x]; }
  __syncthreads();
  int pix = blockIdx.x*256 + threadIdx.x;
  if (pix >= MAPN) return;
  float acc[21];
  #pragma unroll
  for (int i=0;i<21;i++) acc[i]=0.0f;
  const ushort_t* ip = in + (size_t)pix*64;
  #pragma unroll
  for (int cg=0; cg<6; cg++){
    uint4 v = *(const uint4*)(ip + cg*8);
    ushort_t* hv = (ushort_t*)&v;
    #pragma unroll
    for (int j=0;j<8;j++){
      int ci = cg*8+j;
      float s = fmaxf(fmaf(bf2f(hv[j]), sc[ci], sh[ci]), 0.0f);
      #pragma unroll
      for (int co=0;co<21;co++) acc[co]=fmaf(s, sw[co*48+ci], acc[co]);
    }
  }
  #pragma unroll
  for (int co=0;co<21;co++) out[(size_t)co*MAPN + pix] = acc[co] + sb[co];
}

// ---------------- host launch ----------------
static inline size_t al256(size_t x){ return (x + 255) & ~(size_t)255; }

extern "C" void kernel_launch(void* const* d_in, const int* in_sizes, int n_in,
                              void* d_out, int out_size, void* d_ws, size_t ws_size,
                              hipStream_t stream){
  const float* features = (const float*)d_in[0];
  const void*  proj     = d_in[1];
  const void*  mask     = d_in[2];
  const float* rgb      = (const float*)d_in[3];
  const float* w1 = (const float*)d_in[4];
  const float* g1 = (const float*)d_in[5];
  const float* b1 = (const float*)d_in[6];
  const float* w2 = (const float*)d_in[7];
  const float* g2 = (const float*)d_in[8];
  const float* b2 = (const float*)d_in[9];
  const float* w3 = (const float*)d_in[10];
  const float* g3 = (const float*)d_in[11];
  const float* b3 = (const float*)d_in[12];
  const float* w4 = (const float*)d_in[13];
  const float* g4 = (const float*)d_in[14];
  const float* b4 = (const float*)d_in[15];
  const float* w5 = (const float*)d_in[16];
  const float* b5 = (const float*)d_in[17];

  char* ws = (char*)d_ws;
  size_t off = 0;
  unsigned char* mem_f8 = (unsigned char*)(ws + off); off += al256((size_t)MAPN*64);
  ushort_t* actA   = (ushort_t*)(ws + off); off += al256((size_t)MAPN*128*2);
  ushort_t* actB   = (ushort_t*)(ws + off); off += al256((size_t)MAPN*64*2);
  unsigned char* Fhwc = (unsigned char*)(ws + off); off += al256((size_t)131072*64);
  int*      table  = (int*)(ws + off);      off += al256((size_t)NPIX*4);
  unsigned char* wh1 = (unsigned char*)(ws + off); off += al256((size_t)49*64*128);
  unsigned char* wh2 = (unsigned char*)(ws + off); off += al256((size_t)9*128*64);
  unsigned char* wh3 = (unsigned char*)(ws + off); off += al256((size_t)9*64*48);
  unsigned char* wh4 = (unsigned char*)(ws + off); off += al256((size_t)9*64*48);
  float*    partials = (float*)(ws + off);  off += al256((size_t)2048*256*4);
  int* blkSums = (int*)(ws + off); off += al256(2048*4);
  int* blkOffs = (int*)(ws + off); off += al256(2049*4);
  int* maxidx  = (int*)(ws + off); off += 256;
  int* flags   = (int*)(ws + off); off += 256;
  float* scsh1 = (float*)(ws + off); off += al256(256*4);
  float* scsh2 = (float*)(ws + off); off += al256(256*4);
  float* scsh3 = (float*)(ws + off); off += al256(256*4);
  float* scsh4 = (float*)(ws + off); off += al256(256*4);

  float* out_sem = (float*)d_out;
  float* out_obs = out_sem + (size_t)21*MAPN;
  float* out_rgb = out_obs + MAPN;

  detect_kernel<<<1,256,0,stream>>>((const int*)mask, (const int*)proj, flags, maxidx);
  feat_transpose<<<dim3(8,256),256,0,stream>>>(features, Fhwc);

  scan_count<<<2048,256,0,stream>>>(mask, flags, blkSums);
  scan_offsets<<<1,256,0,stream>>>(blkSums, blkOffs);
  build_table<<<2048,256,0,stream>>>(mask, flags, blkOffs, table);

  max_idx_kernel<<<256,256,0,stream>>>(proj, flags, maxidx);

  // merged fp8 fragment-major weight packs (per-CO pow2 scale, absorbed by BN)
  wprep_all<<<288,256,0,stream>>>(w1, wh1, w2, wh2, w3, wh3, w4, wh4);

  gather_kernel<<<62500,256,0,stream>>>(proj, flags, maxidx, table, Fhwc, rgb,
                                        mem_f8, out_obs, out_rgb);

  // L1: 7x7 64->128, fp8 per-kh batch, TR=4, MI=8 x NFW=4 (163 us verified)
  conv2d_f8<64,128,128,7,3,false,64,4,2,2><<<125*8,256,0,stream>>>(mem_f8, wh1, nullptr, actA, partials);
  bn_reduce2<<<128,256,0,stream>>>(partials, 1000, 128, g1, b1, scsh1);

  // L2: 3x3 128->64, fp8 per-kh batch, input-BN(L1)+fp8 fused, TR=4
  conv2d_f8<128,64,64,3,1,true,128,4,2,2><<<125*8,256,0,stream>>>(actA, wh2, scsh1, actB, partials);
  bn_reduce2<<<64,256,0,stream>>>(partials, 1000, 64, g2, b2, scsh2);

  // L3: 3x3 64->48 (pad 64), fp8 per-kh batch, input-BN(L2) fused, TR=4
  conv2d_f8<64,48,64,3,1,true,64,4,4,1><<<125*8,256,0,stream>>>(actB, wh3, scsh2, actA, partials);
  bn_reduce2<<<48,256,0,stream>>>(partials, 1000, 48, g3, b3, scsh3);

  // L4: 3x3 48(pad64)->48, fp8 per-kh batch, input-BN(L3) fused (ci>=48 zeroed), TR=4
  conv2d_f8<64,48,64,3,1,true,48,4,4,1><<<125*8,256,0,stream>>>(actA, wh4, scsh3, actB, partials);
  bn_reduce2<<<48,256,0,stream>>>(partials, 1000, 48, g4, b4, scsh4);

  // L5: 1x1 48->21 + bias, input-BN(L4) fused, fp32, NCHW out
  conv5_kernel<<<(MAPN+255)/256,256,0,stream>>>(actB, w5, b5, scsh4, out_sem);
}

// Round 16
// 423.178 us; speedup vs baseline: 1.0528x; 1.0528x over previous
//
#include <hip/hip_runtime.h>

#define MAPN 250000      // 500*500
#define NPIX 2097152     // 1024*2048

typedef unsigned short ushort_t;
typedef __attribute__((ext_vector_type(4))) float f32x4;

__device__ inline ushort_t f2bf(float f){
  unsigned u = __float_as_uint(f);
  u = (u + 0x7fffu + ((u >> 16) & 1u)) >> 16;
  return (ushort_t)u;
}
__device__ inline float bf2f(ushort_t h){ return __uint_as_float(((unsigned)h) << 16); }

__device__ __forceinline__ void glds16(const void* g, void* l){
  __builtin_amdgcn_global_load_lds((const __attribute__((address_space(1))) unsigned int*)g,
                                   (__attribute__((address_space(3))) unsigned int*)l, 16, 0, 0);
}

// ---------------- input-format helpers ----------------
__device__ inline int read_mask(const void* p, int i, int t){
  if (t==0) return ((const int*)p)[i] != 0;
  if (t==1) return ((const unsigned char*)p)[i] != 0;
  if (t==3) return ((const long long*)p)[i] != 0;
  return ((const float*)p)[i] != 0.0f;
}
__device__ inline int read_idx(const void* p, int i, int t){
  if (t==1) return (int)((const long long*)p)[i];
  return ((const int*)p)[i];
}

__global__ void detect_kernel(const int* __restrict__ mask_w, const int* __restrict__ idx_w,
                              int* __restrict__ flags, int* __restrict__ maxidx){
  int tid = threadIdx.x;
  int orv=0, modd=0, inz=0;
  for (int i=tid;i<4096;i+=256) orv |= mask_w[i];
  for (int i=tid;i<2048;i+=256) modd += (mask_w[2*i+1]!=0);
  for (int i=tid;i<2048;i+=256) inz  += (idx_w[2*i+1]!=0);
  __shared__ int sOr[256], sM[256], sI[256];
  sOr[tid]=orv; sM[tid]=modd; sI[tid]=inz; __syncthreads();
  for (int o=128;o;o>>=1){ if(tid<o){ sOr[tid]|=sOr[tid+o]; sM[tid]+=sM[tid+o]; sI[tid]+=sI[tid+o]; } __syncthreads(); }
  if (tid==0){
    int o = sOr[0];
    int mt;
    if ((o & ~1) == 0)               mt = (sM[0] > 0) ? 0 : 3;
    else if ((o & ~0x01010101) == 0) mt = 1;
    else                             mt = 2;
    flags[0] = mt;
    flags[1] = (sI[0] > 0) ? 0 : 1;
    maxidx[0] = 0;
  }
}

// ---------------- feature transpose CHW -> HWC (fp32 -> bf16) ----------------
__global__ void feat_transpose(const float* __restrict__ f, ushort_t* __restrict__ out){
  __shared__ float tile[64][65];
  int tid = threadIdx.x;
  int y = blockIdx.y;
  int x0 = blockIdx.x * 64;
  #pragma unroll
  for (int pass=0; pass<16; pass++){
    int c = pass*4 + (tid>>6);
    int x = x0 + (tid & 63);
    tile[c][tid & 63] = f[(size_t)c*131072 + (size_t)y*512 + x];
  }
  __syncthreads();
  #pragma unroll
  for (int pass=0; pass<16; pass++){
    int xl = pass*4 + (tid>>6);
    int c  = tid & 63;
    out[((size_t)y*512 + x0 + xl)*64 + c] = f2bf(tile[c][xl]);
  }
}

// ---------------- mask compaction scan ----------------
__global__ void scan_count(const void* __restrict__ mask, const int* __restrict__ flags,
                           int* __restrict__ blkSums){
  int t = flags[0];
  int tid = threadIdx.x;
  int base = blockIdx.x*1024 + tid*4;
  int s = 0;
  #pragma unroll
  for (int j=0;j<4;j++) s += read_mask(mask, base+j, t);
  __shared__ int red[256];
  red[tid] = s; __syncthreads();
  for (int o=128;o;o>>=1){ if (tid<o) red[tid]+=red[tid+o]; __syncthreads(); }
  if (tid==0) blkSums[blockIdx.x] = red[0];
}

__global__ void scan_offsets(const int* __restrict__ blkSums, int* __restrict__ blkOffs){
  __shared__ int tsum[256];
  int tid = threadIdx.x;
  int loc[8]; int s=0;
  #pragma unroll
  for (int j=0;j<8;j++){ loc[j]=blkSums[tid*8+j]; s+=loc[j]; }
  tsum[tid]=s; __syncthreads();
  for (int o=1;o<256;o<<=1){
    int v = (tid>=o)? tsum[tid-o] : 0;
    __syncthreads();
    tsum[tid] += v;
    __syncthreads();
  }
  int run = tsum[tid]-s;
  #pragma unroll
  for (int j=0;j<8;j++){ blkOffs[tid*8+j]=run; run+=loc[j]; }
  if (tid==255) blkOffs[2048]=run;
}

__global__ void build_table(const void* __restrict__ mask, const int* __restrict__ flags,
                            const int* __restrict__ blkOffs, int* __restrict__ table){
  int t = flags[0];
  int tid = threadIdx.x;
  int base = blockIdx.x*1024 + tid*4;
  int mv[4]; int s=0;
  #pragma unroll
  for (int j=0;j<4;j++){ mv[j]=read_mask(mask, base+j, t); s+=mv[j]; }
  __shared__ int red[256];
  red[tid]=s; __syncthreads();
  for (int o=1;o<256;o<<=1){
    int v = (tid>=o)? red[tid-o] : 0;
    __syncthreads();
    red[tid]+=v;
    __syncthreads();
  }
  int excl = red[tid]-s + blkOffs[blockIdx.x];
  int total = blkOffs[2048];
  #pragma unroll
  for (int j=0;j<4;j++){
    int p = base+j;
    int pos;
    if (mv[j]){ pos = excl; excl++; }
    else      { pos = total + (p - excl); }
    table[pos] = p;
  }
}

// ---------------- max(idx) ----------------
__global__ void max_idx_kernel(const void* __restrict__ idxp, const int* __restrict__ flags,
                               int* __restrict__ mx){
  int t = flags[1];
  int m = 0;
  for (int i = blockIdx.x*blockDim.x + threadIdx.x; i < MAPN; i += gridDim.x*blockDim.x)
    m = max(m, read_idx(idxp, i, t));
  #pragma unroll
  for (int o=32;o;o>>=1) m = max(m, __shfl_down(m, o));
  if ((threadIdx.x & 63) == 0) atomicMax(mx, m);
}

// ---------------- gather + on-the-fly bilinear (bf16 in) -> fp8 memory ----------------
__global__ void gather_kernel(const void* __restrict__ idxp, const int* __restrict__ flags,
                              const int* __restrict__ mxp, const int* __restrict__ table,
                              const ushort_t* __restrict__ Fhwc, const float* __restrict__ rgb,
                              unsigned char* __restrict__ mem_f8, float* __restrict__ out_obs,
                              float* __restrict__ out_rgb){
  int cell = blockIdx.x*4 + (threadIdx.x>>6);
  int lane = threadIdx.x & 63;
  int t = flags[1];
  int mx = *mxp;
  int idx = read_idx(idxp, cell, t);
  bool m = idx < mx;
  float v = 0.0f, r = 0.0f;
  if (m){
    int p = table[idx];
    int py = p >> 11, px = p & 2047;
    float fy = py * (255.0f/1023.0f);
    int y0 = (int)fy; float wy = fy - (float)y0; int y1 = min(y0+1, 255);
    float fx = px * (511.0f/2047.0f);
    int x0 = (int)fx; float wx = fx - (float)x0; int x1 = min(x0+1, 511);
    const ushort_t* f00 = Fhwc + ((size_t)y0*512 + x0)*64;
    const ushort_t* f01 = Fhwc + ((size_t)y0*512 + x1)*64;
    const ushort_t* f10 = Fhwc + ((size_t)y1*512 + x0)*64;
    const ushort_t* f11 = Fhwc + ((size_t)y1*512 + x1)*64;
    float w00=(1.0f-wy)*(1.0f-wx), w01=(1.0f-wy)*wx, w10=wy*(1.0f-wx), w11=wy*wx;
    v = w00*bf2f(f00[lane]) + w01*bf2f(f01[lane]) + w10*bf2f(f10[lane]) + w11*bf2f(f11[lane]);
    if (lane < 3) r = rgb[(size_t)p*3 + lane];
  }
  int q = __builtin_amdgcn_cvt_pk_fp8_f32(v, 0.0f, 0, false);
  mem_f8[(size_t)cell*64 + lane] = (unsigned char)(q & 0xff);
  if (lane == 0) out_obs[cell] = m ? 1.0f : 0.0f;
  if (lane < 3)  out_rgb[(size_t)cell*3 + lane] = r;
}

// ---------------- weight prep: OIHW fp32 -> fragment-major fp8, per-CO pow2 scale ----------------
__device__ void wprep_body(const float* __restrict__ w, unsigned char* __restrict__ out,
                           int O, int I, int CIPAD, int KK, int co){
  int n = KK*CIPAD;
  int NFS = (O+15)>>4;
  int KC  = CIPAD>>5;
  float mx = 0.f;
  for (int e=threadIdx.x; e<n; e+=256){
    int ci = e % CIPAD;
    if (ci < I){
      int t = e / CIPAD;
      mx = fmaxf(mx, fabsf(w[((size_t)co*I + ci)*KK + t]));
    }
  }
  __shared__ float red[256];
  red[threadIdx.x]=mx; __syncthreads();
  for (int o=128;o;o>>=1){ if(threadIdx.x<o) red[threadIdx.x]=fmaxf(red[threadIdx.x],red[threadIdx.x+o]); __syncthreads(); }
  float m = red[0];
  float sc = (m > 0.f) ? exp2f(floorf(log2f(224.0f/m))) : 1.0f;
  for (int e=threadIdx.x; e<n; e+=256){
    int t = e / CIPAD, ci = e % CIPAD;
    float v = (ci < I) ? w[((size_t)co*I + ci)*KK + t]*sc : 0.0f;
    int q = __builtin_amdgcn_cvt_pk_fp8_f32(v, 0.0f, 0, false);
    int kc = ci>>5, g=(ci>>3)&3, j=ci&7;
    int l = g*16 + (co&15);
    size_t pos = ((size_t)(t*KC + kc)*NFS + (co>>4))*512 + l*8 + j;
    out[pos] = (unsigned char)(q & 0xff);
  }
}

// merged: blocks 0-127 -> L1, 128-191 -> L2, 192-239 -> L3, 240-287 -> L4
__global__ void wprep_all(const float* __restrict__ w1, unsigned char* __restrict__ o1,
                          const float* __restrict__ w2, unsigned char* __restrict__ o2,
                          const float* __restrict__ w3, unsigned char* __restrict__ o3,
                          const float* __restrict__ w4, unsigned char* __restrict__ o4){
  int b = blockIdx.x;
  if      (b < 128) wprep_body(w1, o1, 128, 64, 64, 49, b);
  else if (b < 192) wprep_body(w2, o2, 64, 128, 128, 9, b-128);
  else if (b < 240) wprep_body(w3, o3, 48, 64, 64, 9, b-192);
  else              wprep_body(w4, o4, 48, 48, 64, 9, b-240);
}

// ---------------- unified 2D-tile fp8 MFMA conv, per-kh B batch (2 barriers/kh) ----------------
template<int CI, int CO, int COPAD, int KS, int PAD, bool HASBN, int CIREAL,
         int TR, int WM, int WN>
__global__ __launch_bounds__(256, 2) void conv2d_f8(const void* __restrict__ in,
                                                    const unsigned char* __restrict__ wt,
                                                    const float* __restrict__ scsh,
                                                    ushort_t* __restrict__ out,
                                                    float* __restrict__ partials){
  constexpr int TCOL = 64;
  constexpr int ECOL = TCOL + 2*PAD;
  constexpr int E    = TR*ECOL;
  constexpr int MF   = TR*4;
  constexpr int MI   = MF/WM;
  constexpr int NFS  = CO/16;
  constexpr int NFW  = NFS/WN;
  constexpr int KC   = CI/32;
  constexpr int CIG  = CI/8;
  constexpr int TB   = CO*CI;
  constexpr int NSL  = TB/1024;
  constexpr int TOT  = E*CIG;
  constexpr int PASSES = (TOT+255)/256;
  constexpr int SCN = HASBN ? CIREAL : 1;

  __shared__ unsigned char sA[E*CI + 128];
  __shared__ unsigned char sB[KS*TB];
  __shared__ float sStat[4][NFW][16][2];
  __shared__ float sSc[SCN], sSh[SCN];

  const int tid = threadIdx.x, lane = tid & 63, wv = tid >> 6;
  const int wm = wv / WN, wn = wv % WN;
  const int cc = blockIdx.x & 7;
  const int rb = blockIdx.x >> 3;
  const int x0 = cc*TCOL, yb = rb*TR;

  const ushort_t* inb = (const ushort_t*)in;
  const unsigned char* in8 = (const unsigned char*)in;

  if (HASBN){
    for (int i=tid;i<CIREAL;i+=256){ sSc[i]=scsh[i]; sSh[i]=scsh[CIREAL+i]; }
    __syncthreads();
  }

  int ebase[MI], frow[MI], fcolb[MI];
  #pragma unroll
  for (int mi=0;mi<MI;mi++){
    int f = wm*MI + mi;
    frow[mi]  = f >> 2;
    fcolb[mi] = (f & 3) * 16;
    ebase[mi] = frow[mi]*ECOL + fcolb[mi] + (lane & 15);
  }

  f32x4 acc[MI][NFW];
  #pragma unroll
  for (int mi=0;mi<MI;mi++)
    #pragma unroll
    for (int ni=0;ni<NFW;ni++) acc[mi][ni] = (f32x4)0.0f;

  for (int kh=0; kh<KS; kh++){
    #pragma unroll
    for (int i=0;i<PASSES;i++){
      int c = i*256 + tid;
      if ((TOT % 256 == 0) || c < TOT){
        int e = c / CIG, ci8 = (c % CIG)*8;
        int row = e / ECOL, col = e % ECOL;
        int yy = yb + row + kh - PAD;
        int xx = x0 + col - PAD;
        uint2 q = make_uint2(0u,0u);
        bool ok = ((unsigned)yy < 500u) && ((unsigned)xx < 500u) && (!HASBN || ci8 < CIREAL);
        if (ok){
          if (HASBN){
            uint4 v = *(const uint4*)(inb + ((size_t)yy*500 + xx)*CI + ci8);
            ushort_t* hv = (ushort_t*)&v;
            float f[8];
            #pragma unroll
            for (int j=0;j<8;j++)
              f[j] = fmaxf(fmaf(bf2f(hv[j]), sSc[ci8+j], sSh[ci8+j]), 0.0f);
            int d0 = __builtin_amdgcn_cvt_pk_fp8_f32(f[0], f[1], 0, false);
            d0     = __builtin_amdgcn_cvt_pk_fp8_f32(f[2], f[3], d0, true);
            int d1 = __builtin_amdgcn_cvt_pk_fp8_f32(f[4], f[5], 0, false);
            d1     = __builtin_amdgcn_cvt_pk_fp8_f32(f[6], f[7], d1, true);
            q = make_uint2((unsigned)d0, (unsigned)d1);
          } else {
            q = *(const uint2*)(in8 + ((size_t)yy*500 + xx)*CI + ci8);
          }
        }
        unsigned wa = ((unsigned)(e*CI + ci8)) ^ ((unsigned)(e&15)<<3);
        *(uint2*)(sA + wa) = q;
      }
    }
    {
      const char* wsrc = (const char*)wt + (size_t)kh*KS*TB;
      for (int s=wv; s<KS*NSL; s+=4)
        glds16(wsrc + (size_t)s*1024 + lane*16, &sB[s*1024]);
    }
    __syncthreads();

    for (int kw=0; kw<KS; kw++){
      const unsigned char* bb = sB + kw*TB;
      #pragma unroll
      for (int kc=0;kc<KC;kc++){
        long long bfr[NFW];
        #pragma unroll
        for (int ni=0;ni<NFW;ni++)
          bfr[ni] = *(const long long*)(bb + (((kc*NFS + wn*NFW + ni)<<9) + lane*8));
        #pragma unroll
        for (int mi=0;mi<MI;mi++){
          int e = ebase[mi] + kw;
          unsigned ra = ((unsigned)(e*CI + kc*32 + (lane>>4)*8)) ^ ((unsigned)(e&15)<<3);
          long long af = *(const long long*)(sA + ra);
          #pragma unroll
          for (int ni=0;ni<NFW;ni++)
            acc[mi][ni] = __builtin_amdgcn_mfma_f32_16x16x32_fp8_fp8(af, bfr[ni], acc[mi][ni], 0,0,0);
        }
      }
    }
    __syncthreads();
  }

  #pragma unroll
  for (int ni=0;ni<NFW;ni++){
    float ps=0.f, pq=0.f;
    #pragma unroll
    for (int mi=0;mi<MI;mi++){
      int colb = fcolb[mi] + (lane>>4)*4;
      size_t rowoff = (size_t)(yb + frow[mi])*500;
      #pragma unroll
      for (int j=0;j<4;j++){
        float v = acc[mi][ni][j];
        int colAbs = x0 + colb + j;
        if (colAbs < 500){
          ps += v; pq += v*v;
          out[(rowoff + colAbs)*COPAD + wn*(NFW*16) + ni*16 + (lane&15)] = f2bf(v);
        }
      }
    }
    ps += __shfl_xor(ps, 16); pq += __shfl_xor(pq, 16);
    ps += __shfl_xor(ps, 32); pq += __shfl_xor(pq, 32);
    if (lane < 16){ sStat[wv][ni][lane][0]=ps; sStat[wv][ni][lane][1]=pq; }
  }
  __syncthreads();
  if (tid < CO){
    int wn_ = tid / (NFW*16);
    int r = tid % (NFW*16);
    int ni_ = r >> 4, col = r & 15;
    float s = 0.f, q = 0.f;
    #pragma unroll
    for (int m=0;m<WM;m++){
      s += sStat[m*WN + wn_][ni_][col][0];
      q += sStat[m*WN + wn_][ni_][col][1];
    }
    partials[(size_t)blockIdx.x*(2*CO) + tid]      = s;
    partials[(size_t)blockIdx.x*(2*CO) + CO + tid] = q;
  }
}

// ---------------- BN: reduce per-block partials -> scale/shift ----------------
__global__ void bn_reduce2(const float* __restrict__ partials, int nblk, int CO,
                           const float* __restrict__ g, const float* __restrict__ b,
                           float* __restrict__ scsh){
  int c = blockIdx.x;
  float s=0.f, q=0.f;
  for (int i=threadIdx.x; i<nblk; i+=256){
    s += partials[(size_t)i*(2*CO) + c];
    q += partials[(size_t)i*(2*CO) + CO + c];
  }
  __shared__ float rs[256], rq[256];
  rs[threadIdx.x]=s; rq[threadIdx.x]=q; __syncthreads();
  for (int o=128;o;o>>=1){
    if (threadIdx.x<o){ rs[threadIdx.x]+=rs[threadIdx.x+o]; rq[threadIdx.x]+=rq[threadIdx.x+o]; }
    __syncthreads();
  }
  if (threadIdx.x==0){
    float mean = rs[0]*(1.0f/(float)MAPN);
    float var  = rq[0]*(1.0f/(float)MAPN) - mean*mean;
    float inv  = rsqrtf(var + 1e-5f);
    float sc   = g[c]*inv;
    scsh[c]    = sc;
    scsh[CO+c] = b[c] - mean*sc;
  }
}

// ---------------- final 1x1 conv + bias (fused input BN+ReLU), fp32, NCHW out ----------------
__global__ void conv5_kernel(const ushort_t* __restrict__ in, const float* __restrict__ w,
                             const float* __restrict__ bias, const float* __restrict__ scsh,
                             float* __restrict__ out){
  __shared__ float sw[21*48];
  __shared__ float sb[21];
  __shared__ float sc[48], sh[48];
  for (int i=threadIdx.x;i<1008;i+=256) sw[i]=w[i];
  if (threadIdx.x<21) sb[threadIdx.x]=bias[threadIdx.x];
  if (threadIdx.x<48){ sc[threadIdx.x]=scsh[threadIdx.x]; sh[threadIdx.x]=scsh[48+threadIdx.x]; }
  __syncthreads();
  int pix = blockIdx.x*256 + threadIdx.x;
  if (pix >= MAPN) return;
  float acc[21];
  #pragma unroll
  for (int i=0;i<21;i++) acc[i]=0.0f;
  const ushort_t* ip = in + (size_t)pix*64;
  #pragma unroll
  for (int cg=0; cg<6; cg++){
    uint4 v = *(const uint4*)(ip + cg*8);
    ushort_t* hv = (ushort_t*)&v;
    #pragma unroll
    for (int j=0;j<8;j++){
      int ci = cg*8+j;
      float s = fmaxf(fmaf(bf2f(hv[j]), sc[ci], sh[ci]), 0.0f);
      #pragma unroll
      for (int co=0;co<21;co++) acc[co]=fmaf(s, sw[co*48+ci], acc[co]);
    }
  }
  #pragma unroll
  for (int co=0;co<21;co++) out[(size_t)co*MAPN + pix] = acc[co] + sb[co];
}

// ---------------- host launch ----------------
static inline size_t al256(size_t x){ return (x + 255) & ~(size_t)255; }

extern "C" void kernel_launch(void* const* d_in, const int* in_sizes, int n_in,
                              void* d_out, int out_size, void* d_ws, size_t ws_size,
                              hipStream_t stream){
  const float* features = (const float*)d_in[0];
  const void*  proj     = d_in[1];
  const void*  mask     = d_in[2];
  const float* rgb      = (const float*)d_in[3];
  const float* w1 = (const float*)d_in[4];
  const float* g1 = (const float*)d_in[5];
  const float* b1 = (const float*)d_in[6];
  const float* w2 = (const float*)d_in[7];
  const float* g2 = (const float*)d_in[8];
  const float* b2 = (const float*)d_in[9];
  const float* w3 = (const float*)d_in[10];
  const float* g3 = (const float*)d_in[11];
  const float* b3 = (const float*)d_in[12];
  const float* w4 = (const float*)d_in[13];
  const float* g4 = (const float*)d_in[14];
  const float* b4 = (const float*)d_in[15];
  const float* w5 = (const float*)d_in[16];
  const float* b5 = (const float*)d_in[17];

  char* ws = (char*)d_ws;
  size_t off = 0;
  unsigned char* mem_f8 = (unsigned char*)(ws + off); off += al256((size_t)MAPN*64);
  ushort_t* actA   = (ushort_t*)(ws + off); off += al256((size_t)MAPN*128*2);
  ushort_t* actB   = (ushort_t*)(ws + off); off += al256((size_t)MAPN*64*2);
  ushort_t* Fhwc   = (ushort_t*)(ws + off); off += al256((size_t)131072*64*2);
  int*      table  = (int*)(ws + off);      off += al256((size_t)NPIX*4);
  unsigned char* wh1 = (unsigned char*)(ws + off); off += al256((size_t)49*64*128);
  unsigned char* wh2 = (unsigned char*)(ws + off); off += al256((size_t)9*128*64);
  unsigned char* wh3 = (unsigned char*)(ws + off); off += al256((size_t)9*64*48);
  unsigned char* wh4 = (unsigned char*)(ws + off); off += al256((size_t)9*64*48);
  float*    partials = (float*)(ws + off);  off += al256((size_t)2048*256*4);
  int* blkSums = (int*)(ws + off); off += al256(2048*4);
  int* blkOffs = (int*)(ws + off); off += al256(2049*4);
  int* maxidx  = (int*)(ws + off); off += 256;
  int* flags   = (int*)(ws + off); off += 256;
  float* scsh1 = (float*)(ws + off); off += al256(256*4);
  float* scsh2 = (float*)(ws + off); off += al256(256*4);
  float* scsh3 = (float*)(ws + off); off += al256(256*4);
  float* scsh4 = (float*)(ws + off); off += al256(256*4);

  float* out_sem = (float*)d_out;
  float* out_obs = out_sem + (size_t)21*MAPN;
  float* out_rgb = out_obs + MAPN;

  detect_kernel<<<1,256,0,stream>>>((const int*)mask, (const int*)proj, flags, maxidx);
  feat_transpose<<<dim3(8,256),256,0,stream>>>(features, Fhwc);

  scan_count<<<2048,256,0,stream>>>(mask, flags, blkSums);
  scan_offsets<<<1,256,0,stream>>>(blkSums, blkOffs);
  build_table<<<2048,256,0,stream>>>(mask, flags, blkOffs, table);

  max_idx_kernel<<<256,256,0,stream>>>(proj, flags, maxidx);

  // merged fp8 fragment-major weight packs (per-CO pow2 scale, absorbed by BN)
  wprep_all<<<288,256,0,stream>>>(w1, wh1, w2, wh2, w3, wh3, w4, wh4);

  gather_kernel<<<62500,256,0,stream>>>(proj, flags, maxidx, table, Fhwc, rgb,
                                        mem_f8, out_obs, out_rgb);

  // L1: 7x7 64->128, fp8 per-kh batch, TR=4, MI=8 x NFW=4 (163 us verified)
  conv2d_f8<64,128,128,7,3,false,64,4,2,2><<<125*8,256,0,stream>>>(mem_f8, wh1, nullptr, actA, partials);
  bn_reduce2<<<128,256,0,stream>>>(partials, 1000, 128, g1, b1, scsh1);

  // L2: 3x3 128->64, fp8 per-kh batch, input-BN(L1)+fp8 fused, TR=4
  conv2d_f8<128,64,64,3,1,true,128,4,2,2><<<125*8,256,0,stream>>>(actA, wh2, scsh1, actB, partials);
  bn_reduce2<<<64,256,0,stream>>>(partials, 1000, 64, g2, b2, scsh2);

  // L3: 3x3 64->48 (pad 64), fp8 per-kh batch, input-BN(L2) fused, TR=4
  conv2d_f8<64,48,64,3,1,true,64,4,4,1><<<125*8,256,0,stream>>>(actB, wh3, scsh2, actA, partials);
  bn_reduce2<<<48,256,0,stream>>>(partials, 1000, 48, g3, b3, scsh3);

  // L4: 3x3 48(pad64)->48, fp8 per-kh batch, input-BN(L3) fused (ci>=48 zeroed), TR=4
  conv2d_f8<64,48,64,3,1,true,48,4,4,1><<<125*8,256,0,stream>>>(actA, wh4, scsh3, actB, partials);
  bn_reduce2<<<48,256,0,stream>>>(partials, 1000, 48, g4, b4, scsh4);

  // L5: 1x1 48->21 + bias, input-BN(L4) fused, fp32, NCHW out
  conv5_kernel<<<(MAPN+255)/256,256,0,stream>>>(actB, w5, b5, scsh4, out_sem);
}

// Round 17
// 420.610 us; speedup vs baseline: 1.0592x; 1.0061x over previous
//
#include <hip/hip_runtime.h>

#define MAPN 250000      // 500*500
#define NPIX 2097152     // 1024*2048

typedef unsigned short ushort_t;
typedef __attribute__((ext_vector_type(4))) float f32x4;

__device__ inline ushort_t f2bf(float f){
  unsigned u = __float_as_uint(f);
  u = (u + 0x7fffu + ((u >> 16) & 1u)) >> 16;
  return (ushort_t)u;
}
__device__ inline float bf2f(ushort_t h){ return __uint_as_float(((unsigned)h) << 16); }

__device__ __forceinline__ void glds16(const void* g, void* l){
  __builtin_amdgcn_global_load_lds((const __attribute__((address_space(1))) unsigned int*)g,
                                   (__attribute__((address_space(3))) unsigned int*)l, 16, 0, 0);
}

// ---------------- input-format helpers ----------------
__device__ inline int read_mask(const void* p, int i, int t){
  if (t==0) return ((const int*)p)[i] != 0;
  if (t==1) return ((const unsigned char*)p)[i] != 0;
  if (t==3) return ((const long long*)p)[i] != 0;
  return ((const float*)p)[i] != 0.0f;
}
__device__ inline int read_idx(const void* p, int i, int t){
  if (t==1) return (int)((const long long*)p)[i];
  return ((const int*)p)[i];
}

__global__ void detect_kernel(const int* __restrict__ mask_w, const int* __restrict__ idx_w,
                              int* __restrict__ flags, int* __restrict__ maxidx){
  int tid = threadIdx.x;
  int orv=0, modd=0, inz=0;
  for (int i=tid;i<4096;i+=256) orv |= mask_w[i];
  for (int i=tid;i<2048;i+=256) modd += (mask_w[2*i+1]!=0);
  for (int i=tid;i<2048;i+=256) inz  += (idx_w[2*i+1]!=0);
  __shared__ int sOr[256], sM[256], sI[256];
  sOr[tid]=orv; sM[tid]=modd; sI[tid]=inz; __syncthreads();
  for (int o=128;o;o>>=1){ if(tid<o){ sOr[tid]|=sOr[tid+o]; sM[tid]+=sM[tid+o]; sI[tid]+=sI[tid+o]; } __syncthreads(); }
  if (tid==0){
    int o = sOr[0];
    int mt;
    if ((o & ~1) == 0)               mt = (sM[0] > 0) ? 0 : 3;
    else if ((o & ~0x01010101) == 0) mt = 1;
    else                             mt = 2;
    flags[0] = mt;
    flags[1] = (sI[0] > 0) ? 0 : 1;
    maxidx[0] = 0;
  }
}

// ---------------- feature transpose CHW -> HWC (fp32 -> bf16) ----------------
__global__ void feat_transpose(const float* __restrict__ f, ushort_t* __restrict__ out){
  __shared__ float tile[64][65];
  int tid = threadIdx.x;
  int y = blockIdx.y;
  int x0 = blockIdx.x * 64;
  #pragma unroll
  for (int pass=0; pass<16; pass++){
    int c = pass*4 + (tid>>6);
    int x = x0 + (tid & 63);
    tile[c][tid & 63] = f[(size_t)c*131072 + (size_t)y*512 + x];
  }
  __syncthreads();
  #pragma unroll
  for (int pass=0; pass<16; pass++){
    int xl = pass*4 + (tid>>6);
    int c  = tid & 63;
    out[((size_t)y*512 + x0 + xl)*64 + c] = f2bf(tile[c][xl]);
  }
}

// ---------------- mask compaction scan ----------------
__global__ void scan_count(const void* __restrict__ mask, const int* __restrict__ flags,
                           int* __restrict__ blkSums){
  int t = flags[0];
  int tid = threadIdx.x;
  int base = blockIdx.x*1024 + tid*4;
  int s = 0;
  #pragma unroll
  for (int j=0;j<4;j++) s += read_mask(mask, base+j, t);
  __shared__ int red[256];
  red[tid] = s; __syncthreads();
  for (int o=128;o;o>>=1){ if (tid<o) red[tid]+=red[tid+o]; __syncthreads(); }
  if (tid==0) blkSums[blockIdx.x] = red[0];
}

__global__ void scan_offsets(const int* __restrict__ blkSums, int* __restrict__ blkOffs){
  __shared__ int tsum[256];
  int tid = threadIdx.x;
  int loc[8]; int s=0;
  #pragma unroll
  for (int j=0;j<8;j++){ loc[j]=blkSums[tid*8+j]; s+=loc[j]; }
  tsum[tid]=s; __syncthreads();
  for (int o=1;o<256;o<<=1){
    int v = (tid>=o)? tsum[tid-o] : 0;
    __syncthreads();
    tsum[tid] += v;
    __syncthreads();
  }
  int run = tsum[tid]-s;
  #pragma unroll
  for (int j=0;j<8;j++){ blkOffs[tid*8+j]=run; run+=loc[j]; }
  if (tid==255) blkOffs[2048]=run;
}

__global__ void build_table(const void* __restrict__ mask, const int* __restrict__ flags,
                            const int* __restrict__ blkOffs, int* __restrict__ table){
  int t = flags[0];
  int tid = threadIdx.x;
  int base = blockIdx.x*1024 + tid*4;
  int mv[4]; int s=0;
  #pragma unroll
  for (int j=0;j<4;j++){ mv[j]=read_mask(mask, base+j, t); s+=mv[j]; }
  __shared__ int red[256];
  red[tid]=s; __syncthreads();
  for (int o=1;o<256;o<<=1){
    int v = (tid>=o)? red[tid-o] : 0;
    __syncthreads();
    red[tid]+=v;
    __syncthreads();
  }
  int excl = red[tid]-s + blkOffs[blockIdx.x];
  int total = blkOffs[2048];
  #pragma unroll
  for (int j=0;j<4;j++){
    int p = base+j;
    int pos;
    if (mv[j]){ pos = excl; excl++; }
    else      { pos = total + (p - excl); }
    table[pos] = p;
  }
}

// ---------------- max(idx) ----------------
__global__ void max_idx_kernel(const void* __restrict__ idxp, const int* __restrict__ flags,
                               int* __restrict__ mx){
  int t = flags[1];
  int m = 0;
  for (int i = blockIdx.x*blockDim.x + threadIdx.x; i < MAPN; i += gridDim.x*blockDim.x)
    m = max(m, read_idx(idxp, i, t));
  #pragma unroll
  for (int o=32;o;o>>=1) m = max(m, __shfl_down(m, o));
  if ((threadIdx.x & 63) == 0) atomicMax(mx, m);
}

// ---------------- gather + on-the-fly bilinear (bf16 in) -> fp8 memory ----------------
__global__ void gather_kernel(const void* __restrict__ idxp, const int* __restrict__ flags,
                              const int* __restrict__ mxp, const int* __restrict__ table,
                              const ushort_t* __restrict__ Fhwc, const float* __restrict__ rgb,
                              unsigned char* __restrict__ mem_f8, float* __restrict__ out_obs,
                              float* __restrict__ out_rgb){
  int cell = blockIdx.x*4 + (threadIdx.x>>6);
  int lane = threadIdx.x & 63;
  int t = flags[1];
  int mx = *mxp;
  int idx = read_idx(idxp, cell, t);
  bool m = idx < mx;
  float v = 0.0f, r = 0.0f;
  if (m){
    int p = table[idx];
    int py = p >> 11, px = p & 2047;
    float fy = py * (255.0f/1023.0f);
    int y0 = (int)fy; float wy = fy - (float)y0; int y1 = min(y0+1, 255);
    float fx = px * (511.0f/2047.0f);
    int x0 = (int)fx; float wx = fx - (float)x0; int x1 = min(x0+1, 511);
    const ushort_t* f00 = Fhwc + ((size_t)y0*512 + x0)*64;
    const ushort_t* f01 = Fhwc + ((size_t)y0*512 + x1)*64;
    const ushort_t* f10 = Fhwc + ((size_t)y1*512 + x0)*64;
    const ushort_t* f11 = Fhwc + ((size_t)y1*512 + x1)*64;
    float w00=(1.0f-wy)*(1.0f-wx), w01=(1.0f-wy)*wx, w10=wy*(1.0f-wx), w11=wy*wx;
    v = w00*bf2f(f00[lane]) + w01*bf2f(f01[lane]) + w10*bf2f(f10[lane]) + w11*bf2f(f11[lane]);
    if (lane < 3) r = rgb[(size_t)p*3 + lane];
  }
  int q = __builtin_amdgcn_cvt_pk_fp8_f32(v, 0.0f, 0, false);
  mem_f8[(size_t)cell*64 + lane] = (unsigned char)(q & 0xff);
  if (lane == 0) out_obs[cell] = m ? 1.0f : 0.0f;
  if (lane < 3)  out_rgb[(size_t)cell*3 + lane] = r;
}

// ---------------- weight prep: OIHW fp32 -> fragment-major fp8, per-CO pow2 scale ----------------
__device__ void wprep_body(const float* __restrict__ w, unsigned char* __restrict__ out,
                           int O, int I, int CIPAD, int KK, int co){
  int n = KK*CIPAD;
  int NFS = (O+15)>>4;
  int KC  = CIPAD>>5;
  float mx = 0.f;
  for (int e=threadIdx.x; e<n; e+=256){
    int ci = e % CIPAD;
    if (ci < I){
      int t = e / CIPAD;
      mx = fmaxf(mx, fabsf(w[((size_t)co*I + ci)*KK + t]));
    }
  }
  __shared__ float red[256];
  red[threadIdx.x]=mx; __syncthreads();
  for (int o=128;o;o>>=1){ if(threadIdx.x<o) red[threadIdx.x]=fmaxf(red[threadIdx.x],red[threadIdx.x+o]); __syncthreads(); }
  float m = red[0];
  float sc = (m > 0.f) ? exp2f(floorf(log2f(224.0f/m))) : 1.0f;
  for (int e=threadIdx.x; e<n; e+=256){
    int t = e / CIPAD, ci = e % CIPAD;
    float v = (ci < I) ? w[((size_t)co*I + ci)*KK + t]*sc : 0.0f;
    int q = __builtin_amdgcn_cvt_pk_fp8_f32(v, 0.0f, 0, false);
    int kc = ci>>5, g=(ci>>3)&3, j=ci&7;
    int l = g*16 + (co&15);
    size_t pos = ((size_t)(t*KC + kc)*NFS + (co>>4))*512 + l*8 + j;
    out[pos] = (unsigned char)(q & 0xff);
  }
}

// merged: blocks 0-127 -> L1, 128-191 -> L2, 192-239 -> L3, 240-287 -> L4
__global__ void wprep_all(const float* __restrict__ w1, unsigned char* __restrict__ o1,
                          const float* __restrict__ w2, unsigned char* __restrict__ o2,
                          const float* __restrict__ w3, unsigned char* __restrict__ o3,
                          const float* __restrict__ w4, unsigned char* __restrict__ o4){
  int b = blockIdx.x;
  if      (b < 128) wprep_body(w1, o1, 128, 64, 64, 49, b);
  else if (b < 192) wprep_body(w2, o2, 64, 128, 128, 9, b-128);
  else if (b < 240) wprep_body(w3, o3, 48, 64, 64, 9, b-192);
  else              wprep_body(w4, o4, 48, 48, 64, 9, b-240);
}

// ---------------- unified 2D-tile fp8 MFMA conv, per-kh B batch (2 barriers/kh) ----------------
// !HASBN path adds T14 async-STAGE: A loads for kh+1 issue right after the mid
// barrier (hide under 7-tap MFMA compute); regs->LDS write happens after the
// trailing barrier. Static-indexed areg (rule #20) keeps it in VGPRs.
template<int CI, int CO, int COPAD, int KS, int PAD, bool HASBN, int CIREAL,
         int TR, int WM, int WN>
__global__ __launch_bounds__(256, 2) void conv2d_f8(const void* __restrict__ in,
                                                    const unsigned char* __restrict__ wt,
                                                    const float* __restrict__ scsh,
                                                    ushort_t* __restrict__ out,
                                                    float* __restrict__ partials){
  constexpr int TCOL = 64;
  constexpr int ECOL = TCOL + 2*PAD;
  constexpr int E    = TR*ECOL;
  constexpr int MF   = TR*4;
  constexpr int MI   = MF/WM;
  constexpr int NFS  = CO/16;
  constexpr int NFW  = NFS/WN;
  constexpr int KC   = CI/32;
  constexpr int CIG  = CI/8;
  constexpr int TB   = CO*CI;
  constexpr int NSL  = TB/1024;
  constexpr int TOT  = E*CIG;
  constexpr int PASSES = (TOT+255)/256;
  constexpr int SCN = HASBN ? CIREAL : 1;

  __shared__ unsigned char sA[E*CI + 128];
  __shared__ unsigned char sB[KS*TB];
  __shared__ float sStat[4][NFW][16][2];
  __shared__ float sSc[SCN], sSh[SCN];

  const int tid = threadIdx.x, lane = tid & 63, wv = tid >> 6;
  const int wm = wv / WN, wn = wv % WN;
  const int cc = blockIdx.x & 7;
  const int rb = blockIdx.x >> 3;
  const int x0 = cc*TCOL, yb = rb*TR;

  const ushort_t* inb = (const ushort_t*)in;
  const unsigned char* in8 = (const unsigned char*)in;

  if (HASBN){
    for (int i=tid;i<CIREAL;i+=256){ sSc[i]=scsh[i]; sSh[i]=scsh[CIREAL+i]; }
    __syncthreads();
  }

  int ebase[MI], frow[MI], fcolb[MI];
  #pragma unroll
  for (int mi=0;mi<MI;mi++){
    int f = wm*MI + mi;
    frow[mi]  = f >> 2;
    fcolb[mi] = (f & 3) * 16;
    ebase[mi] = frow[mi]*ECOL + fcolb[mi] + (lane & 15);
  }

  f32x4 acc[MI][NFW];
  #pragma unroll
  for (int mi=0;mi<MI;mi++)
    #pragma unroll
    for (int ni=0;ni<NFW;ni++) acc[mi][ni] = (f32x4)0.0f;

  if constexpr (!HASBN){
    // ---- T14 pipelined A staging (L1) ----
    uint2 areg[PASSES];
    // prologue: load kh=0 into regs
    #pragma unroll
    for (int i=0;i<PASSES;i++){
      int c = i*256 + tid;
      uint2 q = make_uint2(0u,0u);
      if ((TOT % 256 == 0) || c < TOT){
        int e = c / CIG, ci8 = (c % CIG)*8;
        int row = e / ECOL, col = e % ECOL;
        int yy = yb + row - PAD;
        int xx = x0 + col - PAD;
        if (((unsigned)yy < 500u) && ((unsigned)xx < 500u))
          q = *(const uint2*)(in8 + ((size_t)yy*500 + xx)*CI + ci8);
      }
      areg[i] = q;
    }
    for (int kh=0; kh<KS; kh++){
      // write staged regs to LDS (sA free after trailing barrier of prev kh)
      #pragma unroll
      for (int i=0;i<PASSES;i++){
        int c = i*256 + tid;
        if ((TOT % 256 == 0) || c < TOT){
          int e = c / CIG, ci8 = (c % CIG)*8;
          unsigned wa = ((unsigned)(e*CI + ci8)) ^ ((unsigned)(e&15)<<3);
          *(uint2*)(sA + wa) = areg[i];
        }
      }
      // issue B glds for all taps of this kh
      {
        const char* wsrc = (const char*)wt + (size_t)kh*KS*TB;
        for (int s=wv; s<KS*NSL; s+=4)
          glds16(wsrc + (size_t)s*1024 + lane*16, &sB[s*1024]);
      }
      __syncthreads();   // A + B visible
      // issue next-kh A loads (latency hides under compute)
      if (kh+1 < KS){
        #pragma unroll
        for (int i=0;i<PASSES;i++){
          int c = i*256 + tid;
          uint2 q = make_uint2(0u,0u);
          if ((TOT % 256 == 0) || c < TOT){
            int e = c / CIG, ci8 = (c % CIG)*8;
            int row = e / ECOL, col = e % ECOL;
            int yy = yb + row + (kh+1) - PAD;
            int xx = x0 + col - PAD;
            if (((unsigned)yy < 500u) && ((unsigned)xx < 500u))
              q = *(const uint2*)(in8 + ((size_t)yy*500 + xx)*CI + ci8);
          }
          areg[i] = q;
        }
      }
      // compute all taps of this kh
      for (int kw=0; kw<KS; kw++){
        const unsigned char* bb = sB + kw*TB;
        #pragma unroll
        for (int kc=0;kc<KC;kc++){
          long long bfr[NFW];
          #pragma unroll
          for (int ni=0;ni<NFW;ni++)
            bfr[ni] = *(const long long*)(bb + (((kc*NFS + wn*NFW + ni)<<9) + lane*8));
          #pragma unroll
          for (int mi=0;mi<MI;mi++){
            int e = ebase[mi] + kw;
            unsigned ra = ((unsigned)(e*CI + kc*32 + (lane>>4)*8)) ^ ((unsigned)(e&15)<<3);
            long long af = *(const long long*)(sA + ra);
            #pragma unroll
            for (int ni=0;ni<NFW;ni++)
              acc[mi][ni] = __builtin_amdgcn_mfma_f32_16x16x32_fp8_fp8(af, bfr[ni], acc[mi][ni], 0,0,0);
          }
        }
      }
      __syncthreads();   // compute done before next-kh sA/sB overwrite
    }
  } else {
    // ---- verified round-16 path (BN+ReLU+fp8 fused at stage time) ----
    for (int kh=0; kh<KS; kh++){
      #pragma unroll
      for (int i=0;i<PASSES;i++){
        int c = i*256 + tid;
        if ((TOT % 256 == 0) || c < TOT){
          int e = c / CIG, ci8 = (c % CIG)*8;
          int row = e / ECOL, col = e % ECOL;
          int yy = yb + row + kh - PAD;
          int xx = x0 + col - PAD;
          uint2 q = make_uint2(0u,0u);
          bool ok = ((unsigned)yy < 500u) && ((unsigned)xx < 500u) && (ci8 < CIREAL);
          if (ok){
            uint4 v = *(const uint4*)(inb + ((size_t)yy*500 + xx)*CI + ci8);
            ushort_t* hv = (ushort_t*)&v;
            float f[8];
            #pragma unroll
            for (int j=0;j<8;j++)
              f[j] = fmaxf(fmaf(bf2f(hv[j]), sSc[ci8+j], sSh[ci8+j]), 0.0f);
            int d0 = __builtin_amdgcn_cvt_pk_fp8_f32(f[0], f[1], 0, false);
            d0     = __builtin_amdgcn_cvt_pk_fp8_f32(f[2], f[3], d0, true);
            int d1 = __builtin_amdgcn_cvt_pk_fp8_f32(f[4], f[5], 0, false);
            d1     = __builtin_amdgcn_cvt_pk_fp8_f32(f[6], f[7], d1, true);
            q = make_uint2((unsigned)d0, (unsigned)d1);
          }
          unsigned wa = ((unsigned)(e*CI + ci8)) ^ ((unsigned)(e&15)<<3);
          *(uint2*)(sA + wa) = q;
        }
      }
      {
        const char* wsrc = (const char*)wt + (size_t)kh*KS*TB;
        for (int s=wv; s<KS*NSL; s+=4)
          glds16(wsrc + (size_t)s*1024 + lane*16, &sB[s*1024]);
      }
      __syncthreads();

      for (int kw=0; kw<KS; kw++){
        const unsigned char* bb = sB + kw*TB;
        #pragma unroll
        for (int kc=0;kc<KC;kc++){
          long long bfr[NFW];
          #pragma unroll
          for (int ni=0;ni<NFW;ni++)
            bfr[ni] = *(const long long*)(bb + (((kc*NFS + wn*NFW + ni)<<9) + lane*8));
          #pragma unroll
          for (int mi=0;mi<MI;mi++){
            int e = ebase[mi] + kw;
            unsigned ra = ((unsigned)(e*CI + kc*32 + (lane>>4)*8)) ^ ((unsigned)(e&15)<<3);
            long long af = *(const long long*)(sA + ra);
            #pragma unroll
            for (int ni=0;ni<NFW;ni++)
              acc[mi][ni] = __builtin_amdgcn_mfma_f32_16x16x32_fp8_fp8(af, bfr[ni], acc[mi][ni], 0,0,0);
          }
        }
      }
      __syncthreads();
    }
  }

  // ---- epilogue: bf16 store + fused BN partial stats ----
  #pragma unroll
  for (int ni=0;ni<NFW;ni++){
    float ps=0.f, pq=0.f;
    #pragma unroll
    for (int mi=0;mi<MI;mi++){
      int colb = fcolb[mi] + (lane>>4)*4;
      size_t rowoff = (size_t)(yb + frow[mi])*500;
      #pragma unroll
      for (int j=0;j<4;j++){
        float v = acc[mi][ni][j];
        int colAbs = x0 + colb + j;
        if (colAbs < 500){
          ps += v; pq += v*v;
          out[(rowoff + colAbs)*COPAD + wn*(NFW*16) + ni*16 + (lane&15)] = f2bf(v);
        }
      }
    }
    ps += __shfl_xor(ps, 16); pq += __shfl_xor(pq, 16);
    ps += __shfl_xor(ps, 32); pq += __shfl_xor(pq, 32);
    if (lane < 16){ sStat[wv][ni][lane][0]=ps; sStat[wv][ni][lane][1]=pq; }
  }
  __syncthreads();
  if (tid < CO){
    int wn_ = tid / (NFW*16);
    int r = tid % (NFW*16);
    int ni_ = r >> 4, col = r & 15;
    float s = 0.f, q = 0.f;
    #pragma unroll
    for (int m=0;m<WM;m++){
      s += sStat[m*WN + wn_][ni_][col][0];
      q += sStat[m*WN + wn_][ni_][col][1];
    }
    partials[(size_t)blockIdx.x*(2*CO) + tid]      = s;
    partials[(size_t)blockIdx.x*(2*CO) + CO + tid] = q;
  }
}

// ---------------- BN: reduce per-block partials -> scale/shift ----------------
__global__ void bn_reduce2(const float* __restrict__ partials, int nblk, int CO,
                           const float* __restrict__ g, const float* __restrict__ b,
                           float* __restrict__ scsh){
  int c = blockIdx.x;
  float s=0.f, q=0.f;
  for (int i=threadIdx.x; i<nblk; i+=256){
    s += partials[(size_t)i*(2*CO) + c];
    q += partials[(size_t)i*(2*CO) + CO + c];
  }
  __shared__ float rs[256], rq[256];
  rs[threadIdx.x]=s; rq[threadIdx.x]=q; __syncthreads();
  for (int o=128;o;o>>=1){
    if (threadIdx.x<o){ rs[threadIdx.x]+=rs[threadIdx.x+o]; rq[threadIdx.x]+=rq[threadIdx.x+o]; }
    __syncthreads();
  }
  if (threadIdx.x==0){
    float mean = rs[0]*(1.0f/(float)MAPN);
    float var  = rq[0]*(1.0f/(float)MAPN) - mean*mean;
    float inv  = rsqrtf(var + 1e-5f);
    float sc   = g[c]*inv;
    scsh[c]    = sc;
    scsh[CO+c] = b[c] - mean*sc;
  }
}

// ---------------- final 1x1 conv + bias (fused input BN+ReLU), fp32, NCHW out ----------------
__global__ void conv5_kernel(const ushort_t* __restrict__ in, const float* __restrict__ w,
                             const float* __restrict__ bias, const float* __restrict__ scsh,
                             float* __restrict__ out){
  __shared__ float sw[21*48];
  __shared__ float sb[21];
  __shared__ float sc[48], sh[48];
  for (int i=threadIdx.x;i<1008;i+=256) sw[i]=w[i];
  if (threadIdx.x<21) sb[threadIdx.x]=bias[threadIdx.x];
  if (threadIdx.x<48){ sc[threadIdx.x]=scsh[threadIdx.x]; sh[threadIdx.x]=scsh[48+threadIdx.x]; }
  __syncthreads();
  int pix = blockIdx.x*256 + threadIdx.x;
  if (pix >= MAPN) return;
  float acc[21];
  #pragma unroll
  for (int i=0;i<21;i++) acc[i]=0.0f;
  const ushort_t* ip = in + (size_t)pix*64;
  #pragma unroll
  for (int cg=0; cg<6; cg++){
    uint4 v = *(const uint4*)(ip + cg*8);
    ushort_t* hv = (ushort_t*)&v;
    #pragma unroll
    for (int j=0;j<8;j++){
      int ci = cg*8+j;
      float s = fmaxf(fmaf(bf2f(hv[j]), sc[ci], sh[ci]), 0.0f);
      #pragma unroll
      for (int co=0;co<21;co++) acc[co]=fmaf(s, sw[co*48+ci], acc[co]);
    }
  }
  #pragma unroll
  for (int co=0;co<21;co++) out[(size_t)co*MAPN + pix] = acc[co] + sb[co];
}

// ---------------- host launch ----------------
static inline size_t al256(size_t x){ return (x + 255) & ~(size_t)255; }

extern "C" void kernel_launch(void* const* d_in, const int* in_sizes, int n_in,
                              void* d_out, int out_size, void* d_ws, size_t ws_size,
                              hipStream_t stream){
  const float* features = (const float*)d_in[0];
  const void*  proj     = d_in[1];
  const void*  mask     = d_in[2];
  const float* rgb      = (const float*)d_in[3];
  const float* w1 = (const float*)d_in[4];
  const float* g1 = (const float*)d_in[5];
  const float* b1 = (const float*)d_in[6];
  const float* w2 = (const float*)d_in[7];
  const float* g2 = (const float*)d_in[8];
  const float* b2 = (const float*)d_in[9];
  const float* w3 = (const float*)d_in[10];
  const float* g3 = (const float*)d_in[11];
  const float* b3 = (const float*)d_in[12];
  const float* w4 = (const float*)d_in[13];
  const float* g4 = (const float*)d_in[14];
  const float* b4 = (const float*)d_in[15];
  const float* w5 = (const float*)d_in[16];
  const float* b5 = (const float*)d_in[17];

  char* ws = (char*)d_ws;
  size_t off = 0;
  unsigned char* mem_f8 = (unsigned char*)(ws + off); off += al256((size_t)MAPN*64);
  ushort_t* actA   = (ushort_t*)(ws + off); off += al256((size_t)MAPN*128*2);
  ushort_t* actB   = (ushort_t*)(ws + off); off += al256((size_t)MAPN*64*2);
  ushort_t* Fhwc   = (ushort_t*)(ws + off); off += al256((size_t)131072*64*2);
  int*      table  = (int*)(ws + off);      off += al256((size_t)NPIX*4);
  unsigned char* wh1 = (unsigned char*)(ws + off); off += al256((size_t)49*64*128);
  unsigned char* wh2 = (unsigned char*)(ws + off); off += al256((size_t)9*128*64);
  unsigned char* wh3 = (unsigned char*)(ws + off); off += al256((size_t)9*64*48);
  unsigned char* wh4 = (unsigned char*)(ws + off); off += al256((size_t)9*64*48);
  float*    partials = (float*)(ws + off);  off += al256((size_t)2048*256*4);
  int* blkSums = (int*)(ws + off); off += al256(2048*4);
  int* blkOffs = (int*)(ws + off); off += al256(2049*4);
  int* maxidx  = (int*)(ws + off); off += 256;
  int* flags   = (int*)(ws + off); off += 256;
  float* scsh1 = (float*)(ws + off); off += al256(256*4);
  float* scsh2 = (float*)(ws + off); off += al256(256*4);
  float* scsh3 = (float*)(ws + off); off += al256(256*4);
  float* scsh4 = (float*)(ws + off); off += al256(256*4);

  float* out_sem = (float*)d_out;
  float* out_obs = out_sem + (size_t)21*MAPN;
  float* out_rgb = out_obs + MAPN;

  detect_kernel<<<1,256,0,stream>>>((const int*)mask, (const int*)proj, flags, maxidx);
  feat_transpose<<<dim3(8,256),256,0,stream>>>(features, Fhwc);

  scan_count<<<2048,256,0,stream>>>(mask, flags, blkSums);
  scan_offsets<<<1,256,0,stream>>>(blkSums, blkOffs);
  build_table<<<2048,256,0,stream>>>(mask, flags, blkOffs, table);

  max_idx_kernel<<<256,256,0,stream>>>(proj, flags, maxidx);

  // merged fp8 fragment-major weight packs (per-CO pow2 scale, absorbed by BN)
  wprep_all<<<288,256,0,stream>>>(w1, wh1, w2, wh2, w3, wh3, w4, wh4);

  gather_kernel<<<62500,256,0,stream>>>(proj, flags, maxidx, table, Fhwc, rgb,
                                        mem_f8, out_obs, out_rgb);

  // L1: 7x7 64->128, fp8 per-kh batch + T14 staged-load pipeline
  conv2d_f8<64,128,128,7,3,false,64,4,2,2><<<125*8,256,0,stream>>>(mem_f8, wh1, nullptr, actA, partials);
  bn_reduce2<<<128,256,0,stream>>>(partials, 1000, 128, g1, b1, scsh1);

  // L2: 3x3 128->64, fp8 per-kh batch, input-BN(L1)+fp8 fused, TR=4
  conv2d_f8<128,64,64,3,1,true,128,4,2,2><<<125*8,256,0,stream>>>(actA, wh2, scsh1, actB, partials);
  bn_reduce2<<<64,256,0,stream>>>(partials, 1000, 64, g2, b2, scsh2);

  // L3: 3x3 64->48 (pad 64), fp8 per-kh batch, input-BN(L2) fused, TR=4
  conv2d_f8<64,48,64,3,1,true,64,4,4,1><<<125*8,256,0,stream>>>(actB, wh3, scsh2, actA, partials);
  bn_reduce2<<<48,256,0,stream>>>(partials, 1000, 48, g3, b3, scsh3);

  // L4: 3x3 48(pad64)->48, fp8 per-kh batch, input-BN(L3) fused (ci>=48 zeroed), TR=4
  conv2d_f8<64,48,64,3,1,true,48,4,4,1><<<125*8,256,0,stream>>>(actA, wh4, scsh3, actB, partials);
  bn_reduce2<<<48,256,0,stream>>>(partials, 1000, 48, g4, b4, scsh4);

  // L5: 1x1 48->21 + bias, input-BN(L4) fused, fp32, NCHW out
  conv5_kernel<<<(MAPN+255)/256,256,0,stream>>>(actB, w5, b5, scsh4, out_sem);
}